// Round 16
// baseline (775.512 us; speedup 1.0000x reference)
//
#include <hip/hip_runtime.h>
#include <hip/hip_bf16.h>
#include <stdint.h>

#define S_TOK 32768
#define M_DIM 512
#define E_NUM 64
#define V_DIM 2048
#define CAP   1024

typedef __attribute__((ext_vector_type(8))) short short8;
typedef __attribute__((ext_vector_type(4))) float f32x4;

__device__ __forceinline__ unsigned short f2bf(float f) {
  unsigned int u = __float_as_uint(f);
  unsigned int r = (u + 0x7fffu + ((u >> 16) & 1u)) >> 16;
  return (unsigned short)r;
}
__device__ __forceinline__ float bf2f(unsigned short h) {
  return __uint_as_float(((unsigned int)h) << 16);
}

__device__ __forceinline__ void gload16(const void* g, void* lds) {
  __builtin_amdgcn_global_load_lds(
      (const __attribute__((address_space(1))) void*)g,
      (__attribute__((address_space(3))) void*)lds, 16, 0, 0);
}

// ---------------- wg [64][512] -> wgT [512][64] (one-time, 128 KB) ----------------
__global__ __launch_bounds__(256) void wgt_kernel(const float* __restrict__ wg,
                                                  float* __restrict__ wgT) {
  int idx = blockIdx.x * 256 + threadIdx.x;   // 0..32767
  int m = idx >> 6, e = idx & 63;
  wgT[idx] = wg[e * M_DIM + m];               // writes coalesced; reads once
}

// ===== prep: gating (blocks 0..4095, 8 tokens) + weight transposes (64x64 tiles) =====
// Union shrunk to ~18 KB -> 8 blocks/CU so BW-bound transpose blocks get TLP.
// Gating keeps f32 x LDS stage (R9 lesson) + coalesced wgT reads (R15 win).
#define GATE_BLKS (S_TOK / 8)            // 4096
#define TR_BLKS   32768                  // 16384 tiles per matrix (64x64 each)

struct PrepSmem {
  union {
    float ts[64][65];                    // transpose tile: 16.64 KB
    struct {
      float4 xs4[8 * 128];               // 8 tokens x 512 f32: 16 KB
      float mered[4][64];                // 1 KB
      int cered[4][64];                  // 1 KB
    } g;
  };
};

__global__ __launch_bounds__(256) void prep_kernel(
    const float* __restrict__ x, const float* __restrict__ wgT,
    int* __restrict__ topk, float* __restrict__ gates_n,
    float* __restrict__ me_part, int* __restrict__ ce_part,
    unsigned short* __restrict__ xbf,
    const float* __restrict__ w1, unsigned short* __restrict__ o1,
    const float* __restrict__ w2, unsigned short* __restrict__ o2) {
  __shared__ PrepSmem sm;
  int tid = threadIdx.x;

  if (blockIdx.x >= GATE_BLKS) {
    // ---------------- transpose tile: 64x64 ----------------
    int t = blockIdx.x - GATE_BLKS;          // 0..32767
    int which = t >> 14;                     // 16384 tiles per matrix
    t &= 16383;
    int R = which ? V_DIM : M_DIM;
    int Cc = which ? M_DIM : V_DIM;
    int nbx = Cc / 64;
    int b = t >> 8;                          // 256 tiles per expert
    int tt = t & 255;
    const float* ip = (which ? w2 : w1) + (size_t)b * R * Cc;
    unsigned short* op = (which ? o2 : o1) + (size_t)b * R * Cc;
    int c0 = (tt % nbx) * 64, r0 = (tt / nbx) * 64;
    #pragma unroll
    for (int i = 0; i < 4; ++i) {
      int chunk = i * 256 + tid;
      int row = chunk >> 4;                  // 0..63
      int c4 = (chunk & 15) * 4;
      float4 v = *reinterpret_cast<const float4*>(&ip[(size_t)(r0 + row) * Cc + c0 + c4]);
      sm.ts[row][c4 + 0] = v.x; sm.ts[row][c4 + 1] = v.y;
      sm.ts[row][c4 + 2] = v.z; sm.ts[row][c4 + 3] = v.w;
    }
    __syncthreads();
    #pragma unroll
    for (int i = 0; i < 2; ++i) {
      int chunk = i * 256 + tid;
      int c = chunk >> 3;                    // 0..63 (output row)
      int rg = (chunk & 7) * 8;              // 0..56 (output col group)
      short8 o;
      #pragma unroll
      for (int j = 0; j < 8; ++j) o[j] = (short)f2bf(sm.ts[rg + j][c]);
      *reinterpret_cast<short8*>(&op[(size_t)(c0 + c) * R + r0 + rg]) = o;
    }
    return;
  }

  // ------------- gating: 8 tokens/block, x in LDS, wgT coalesced + prefetched -------------
  int l = tid & 63, w = tid >> 6;
  int tb = blockIdx.x * 8;
  const float4* xg4 = reinterpret_cast<const float4*>(x) + (size_t)tb * 128;
  ushort4* xb4 = reinterpret_cast<ushort4*>(xbf) + (size_t)tb * 128;
  #pragma unroll
  for (int i = 0; i < 4; ++i) {
    float4 v = xg4[i * 256 + tid];
    sm.g.xs4[i * 256 + tid] = v;
    ushort4 o;
    o.x = f2bf(v.x); o.y = f2bf(v.y); o.z = f2bf(v.z); o.w = f2bf(v.w);
    xb4[i * 256 + tid] = o;   // fused x -> bf16
  }
  __syncthreads();

  const float* wgtp = wgT + l;
  const float* xsf = reinterpret_cast<const float*>(sm.g.xs4);
  float acc[2] = {0.f, 0.f};
  for (int i0 = 0; i0 < 512; i0 += 8) {
    float wv[8];
    #pragma unroll
    for (int u = 0; u < 8; ++u) wv[u] = wgtp[(i0 + u) * 64];
    #pragma unroll
    for (int u = 0; u < 8; ++u) {
      #pragma unroll
      for (int t = 0; t < 2; ++t)
        acc[t] += xsf[(w * 2 + t) * 512 + i0 + u] * wv[u];
    }
  }

  float melocal = 0.f;
  int celocal = 0;
  #pragma unroll
  for (int t = 0; t < 2; ++t) {
    float v = acc[t];
    float bv = v; int bi = l;
    #pragma unroll
    for (int off = 32; off; off >>= 1) {
      float ov = __shfl_xor(bv, off);
      int oi = __shfl_xor(bi, off);
      if (ov > bv || (ov == bv && oi < bi)) { bv = ov; bi = oi; }
    }
    float v2 = (l == bi) ? -INFINITY : v;
    float bv2 = v2; int bi2 = l;
    #pragma unroll
    for (int off = 32; off; off >>= 1) {
      float ov = __shfl_xor(bv2, off);
      int oi = __shfl_xor(bi2, off);
      if (ov > bv2 || (ov == bv2 && oi < bi2)) { bv2 = ov; bi2 = oi; }
    }
    float ex = expf(v - bv);
    float s = ex;
    #pragma unroll
    for (int off = 32; off; off >>= 1) s += __shfl_xor(s, off);
    melocal += ex / s;
    if (l == bi) celocal += 1;
    if (l == 0) {
      int sidx = tb + w * 2 + t;
      topk[sidx * 2 + 0] = bi;
      topk[sidx * 2 + 1] = bi2;
      float g1 = 1.0f / s;
      float g2 = expf(bv2 - bv) / s;
      float denom = fmaxf(g1 + g2, 1.1920929e-07f);
      gates_n[sidx * 2 + 0] = g1 / denom;
      gates_n[sidx * 2 + 1] = g2 / denom;
    }
  }
  sm.g.mered[w][l] = melocal;
  sm.g.cered[w][l] = celocal;
  __syncthreads();
  if (tid < 64) {
    me_part[blockIdx.x * 64 + tid] =
        sm.g.mered[0][tid] + sm.g.mered[1][tid] + sm.g.mered[2][tid] + sm.g.mered[3][tid];
    ce_part[blockIdx.x * 64 + tid] =
        sm.g.cered[0][tid] + sm.g.cered[1][tid] + sm.g.cered[2][tid] + sm.g.cered[3][tid];
  }
}

// ---------------- capacity ranking (self-initializing slot_map) ----------------
__global__ __launch_bounds__(256) void rank_kernel(const int* __restrict__ topk,
                                                   int* __restrict__ dest,
                                                   int* __restrict__ slot_map) {
  int e = blockIdx.x;
  int tid = threadIdx.x;
  int l = tid & 63, w = tid >> 6;
  int4 minus1 = {-1, -1, -1, -1};
  reinterpret_cast<int4*>(slot_map + e * CAP)[tid] = minus1;

  const int2* tk = reinterpret_cast<const int2*>(topk);
  int base = tid * 128;
  int c0 = 0, c1 = 0;
  for (int j = 0; j < 128; ++j) {
    int2 p = tk[base + j];
    c0 += (p.x == e); c1 += (p.y == e);
  }
  int i0 = c0, i1 = c1;
  #pragma unroll
  for (int off = 1; off < 64; off <<= 1) {
    int t0 = __shfl_up(i0, off);
    int t1 = __shfl_up(i1, off);
    if (l >= off) { i0 += t0; i1 += t1; }
  }
  __shared__ int ws0[4], ws1[4], wo0[4], wo1[4], tot0s;
  if (l == 63) { ws0[w] = i0; ws1[w] = i1; }
  __syncthreads();
  if (tid == 0) {
    int a = 0, b = 0;
    #pragma unroll
    for (int j = 0; j < 4; ++j) { wo0[j] = a; a += ws0[j]; wo1[j] = b; b += ws1[j]; }
    tot0s = a;
  }
  __syncthreads();
  int loc0 = wo0[w] + i0 - c0;
  int loc1 = tot0s + wo1[w] + i1 - c1;
  for (int j = 0; j < 128; ++j) {
    int s = base + j;
    int2 p = tk[s];
    if (p.x == e) {
      int d = (loc0 < CAP) ? e * CAP + loc0 : -1;
      dest[s * 2] = d;
      if (d >= 0) slot_map[d] = s;
      loc0++;
    }
    if (p.y == e) {
      int d = (loc1 < CAP) ? e * CAP + loc1 : -1;
      dest[s * 2 + 1] = d;
      if (d >= 0) slot_map[d] = s;
      loc1++;
    }
  }
}

// =================== 256x256 8-phase MFMA GEMM (T2+T3+T4+T5) — round-6 proven ===================
#define PH_TOP                                                                 \
  __builtin_amdgcn_sched_barrier(0);                                           \
  __builtin_amdgcn_s_barrier();                                                \
  asm volatile("s_waitcnt lgkmcnt(0)" ::: "memory");                           \
  __builtin_amdgcn_sched_barrier(0);                                           \
  __builtin_amdgcn_s_setprio(1);
#define PH_BOT                                                                 \
  __builtin_amdgcn_s_setprio(0);                                               \
  __builtin_amdgcn_sched_barrier(0);                                           \
  __builtin_amdgcn_s_barrier();

struct SmemGemm {
  union {
    struct {
      unsigned short A[2][256 * 64];
      unsigned short B[2][256 * 64];
    } st;
    unsigned short C[256 * 258];  // epilogue staging
  };
};

template <int KD, int ND, int NBX, int NBY, bool GATHER, bool RELU>
__global__ __launch_bounds__(512, 2) void gemm8_kernel(
    const unsigned short* __restrict__ A,
    const unsigned short* __restrict__ BT,
    const float* __restrict__ bias,
    const int* __restrict__ slot_map,
    unsigned short* __restrict__ out) {
  constexpr int NT = KD / 64;  // K-tiles
  __shared__ SmemGemm sm;

  const int tid = threadIdx.x;
  const int l = tid & 63;
  const int w = tid >> 6;
  const int wm = w >> 2;
  const int wn = w & 3;
  const int lr = l & 15;
  const int lk8 = l >> 4;

  // XCD-chunked bijective block swizzle: concurrent lids on one XCD = one expert (L2-fit)
  const int nwg = E_NUM * NBX * NBY;
  const int cpx = nwg >> 3;
  int lid = ((int)blockIdx.x % 8) * cpx + (int)blockIdx.x / 8;
  const int e = lid / (NBX * NBY);
  int rem = lid % (NBX * NBY);
  const int n0 = (rem / NBY) * 256;
  const int r0 = (rem % NBY) * 256;

  // stage swizzle: LDS group (l&7) at row r holds global colgroup (l&7)^(r&7)
  const int cg8 = (((l & 7) ^ (l >> 3)) * 8);

  uint32_t offA[2][2], offB[2][2], ldsA[2][2], ldsB[2][2];
  #pragma unroll
  for (int sel = 0; sel < 2; ++sel) {
    #pragma unroll
    for (int i = 0; i < 2; ++i) {
      int lr128 = i * 64 + w * 8 + (l >> 3);
      int ar = ((lr128 >> 6) * 128) + sel * 64 + (lr128 & 63);
      int br = ((lr128 >> 5) * 64) + sel * 32 + (lr128 & 31);
      ldsA[sel][i] = ar * 64 + (l & 7) * 8;
      ldsB[sel][i] = br * 64 + (l & 7) * 8;
      int arow;
      if (GATHER) {
        int s = slot_map[e * CAP + r0 + ar];
        if (s < 0) s = 0;  // unfilled slot: any valid row; output never read
        arow = s;
      } else {
        arow = e * CAP + r0 + ar;
      }
      offA[sel][i] = (uint32_t)arow * KD + cg8;
      offB[sel][i] = (uint32_t)(n0 + br) * KD + cg8;
    }
  }
  const unsigned short* Bexp = BT + (size_t)e * ND * KD;

  const int sg0 = ((0 + lk8) ^ (lr & 7)) * 8;
  const int sg1 = ((4 + lk8) ^ (lr & 7)) * 8;

#define STAGE_A(sel, p, kt)                                                    \
  do {                                                                         \
    gload16(A + offA[sel][0] + (kt) * 64, &sm.st.A[p][ldsA[sel][0]]);          \
    gload16(A + offA[sel][1] + (kt) * 64, &sm.st.A[p][ldsA[sel][1]]);          \
  } while (0)
#define STAGE_B(sel, p, kt)                                                    \
  do {                                                                         \
    gload16(Bexp + offB[sel][0] + (kt) * 64, &sm.st.B[p][ldsB[sel][0]]);       \
    gload16(Bexp + offB[sel][1] + (kt) * 64, &sm.st.B[p][ldsB[sel][1]]);       \
  } while (0)
#define RD_A(p, mh, mi, ks)                                                    \
  (*reinterpret_cast<const short8*>(                                           \
      &sm.st.A[p][(wm * 128 + (mh) * 64 + (mi) * 16 + lr) * 64 + ((ks) ? sg1 : sg0)]))
#define RD_B(p, nh, ni, ks)                                                    \
  (*reinterpret_cast<const short8*>(                                           \
      &sm.st.B[p][(wn * 64 + (nh) * 32 + (ni) * 16 + lr) * 64 + ((ks) ? sg1 : sg0)]))

  short8 afr[2][4][2];
  short8 bfr[2][2];
  f32x4 acc[8][4];
  f32x4 zero = {0.f, 0.f, 0.f, 0.f};
  #pragma unroll
  for (int m = 0; m < 8; ++m)
    #pragma unroll
    for (int n = 0; n < 4; ++n) acc[m][n] = zero;

  // prologue: tile0 complete + tile1 {Amh0, Amh1, Bnh0}  (14 vmem ops)
  STAGE_A(0, 0, 0); STAGE_A(1, 0, 0); STAGE_B(0, 0, 0); STAGE_B(1, 0, 0);
  STAGE_A(0, 1, 1); STAGE_A(1, 1, 1); STAGE_B(0, 1, 1);
  asm volatile("s_waitcnt vmcnt(6)" ::: "memory");
  __builtin_amdgcn_sched_barrier(0);
  __builtin_amdgcn_s_barrier();

#define GROUP(k, p)                                                            \
  {                                                                            \
    /* phase 1: quadrant (mh0, nh0); stage Bnh1(k+1) -> dbuf[p^1] */           \
    _Pragma("unroll") for (int mi = 0; mi < 4; ++mi) {                         \
      afr[0][mi][0] = RD_A(p, 0, mi, 0);                                       \
      afr[0][mi][1] = RD_A(p, 0, mi, 1);                                       \
    }                                                                          \
    _Pragma("unroll") for (int ni = 0; ni < 2; ++ni) {                         \
      bfr[ni][0] = RD_B(p, 0, ni, 0);                                          \
      bfr[ni][1] = RD_B(p, 0, ni, 1);                                          \
    }                                                                          \
    if ((k) + 1 < NT) { STAGE_B(1, (p) ^ 1, (k) + 1); }                        \
    PH_TOP                                                                     \
    _Pragma("unroll") for (int mi = 0; mi < 4; ++mi)                           \
      _Pragma("unroll") for (int ni = 0; ni < 2; ++ni) {                       \
        acc[mi][ni] = __builtin_amdgcn_mfma_f32_16x16x32_bf16(                 \
            afr[0][mi][0], bfr[ni][0], acc[mi][ni], 0, 0, 0);                  \
        acc[mi][ni] = __builtin_amdgcn_mfma_f32_16x16x32_bf16(                 \
            afr[0][mi][1], bfr[ni][1], acc[mi][ni], 0, 0, 0);                  \
      }                                                                        \
    PH_BOT                                                                     \
    /* phase 2: quadrant (mh1, nh0); stage Amh0(k+2) -> dbuf[p] */             \
    _Pragma("unroll") for (int mi = 0; mi < 4; ++mi) {                         \
      afr[1][mi][0] = RD_A(p, 1, mi, 0);                                       \
      afr[1][mi][1] = RD_A(p, 1, mi, 1);                                       \
    }                                                                          \
    if ((k) + 2 < NT) { STAGE_A(0, p, (k) + 2); }                              \
    PH_TOP                                                                     \
    _Pragma("unroll") for (int mi = 0; mi < 4; ++mi)                           \
      _Pragma("unroll") for (int ni = 0; ni < 2; ++ni) {                       \
        acc[4 + mi][ni] = __builtin_amdgcn_mfma_f32_16x16x32_bf16(             \
            afr[1][mi][0], bfr[ni][0], acc[4 + mi][ni], 0, 0, 0);              \
        acc[4 + mi][ni] = __builtin_amdgcn_mfma_f32_16x16x32_bf16(             \
            afr[1][mi][1], bfr[ni][1], acc[4 + mi][ni], 0, 0, 0);              \
      }                                                                        \
    PH_BOT                                                                     \
    /* phase 3: quadrant (mh0, nh1); stage Amh1(k+2) -> dbuf[p] */             \
    _Pragma("unroll") for (int ni = 0; ni < 2; ++ni) {                         \
      bfr[ni][0] = RD_B(p, 1, ni, 0);                                          \
      bfr[ni][1] = RD_B(p, 1, ni, 1);                                          \
    }                                                                          \
    if ((k) + 2 < NT) { STAGE_A(1, p, (k) + 2); }                              \
    PH_TOP                                                                     \
    _Pragma("unroll") for (int mi = 0; mi < 4; ++mi)                           \
      _Pragma("unroll") for (int ni = 0; ni < 2; ++ni) {                       \
        acc[mi][2 + ni] = __builtin_amdgcn_mfma_f32_16x16x32_bf16(             \
            afr[0][mi][0], bfr[ni][0], acc[mi][2 + ni], 0, 0, 0);              \
        acc[mi][2 + ni] = __builtin_amdgcn_mfma_f32_16x16x32_bf16(             \
            afr[0][mi][1], bfr[ni][1], acc[mi][2 + ni], 0, 0, 0);              \
      }                                                                        \
    PH_BOT                                                                     \
    /* phase 4: quadrant (mh1, nh1); stage Bnh0(k+2); counted vmcnt */         \
    if ((k) + 2 < NT) { STAGE_B(0, p, (k) + 2); }                              \
    __builtin_amdgcn_sched_barrier(0);                                         \
    __builtin_amdgcn_s_barrier();                                              \
    __builtin_amdgcn_s_setprio(1);                                             \
    _Pragma("unroll") for (int mi = 0; mi < 4; ++mi)                           \
      _Pragma("unroll") for (int ni = 0; ni < 2; ++ni) {                       \
        acc[4 + mi][2 + ni] = __builtin_amdgcn_mfma_f32_16x16x32_bf16(         \
            afr[1][mi][0], bfr[ni][0], acc[4 + mi][2 + ni], 0, 0, 0);          \
        acc[4 + mi][2 + ni] = __builtin_amdgcn_mfma_f32_16x16x32_bf16(         \
            afr[1][mi][1], bfr[ni][1], acc[4 + mi][2 + ni], 0, 0, 0);          \
      }                                                                        \
    __builtin_amdgcn_s_setprio(0);                                             \
    __builtin_amdgcn_sched_barrier(0);                                         \
    if ((k) + 2 < NT) {                                                        \
      asm volatile("s_waitcnt vmcnt(6)" ::: "memory");                         \
    } else {                                                                   \
      asm volatile("s_waitcnt vmcnt(0)" ::: "memory");                         \
    }                                                                          \
    __builtin_amdgcn_sched_barrier(0);                                         \
    __builtin_amdgcn_s_barrier();                                              \
  }

  for (int kk = 0; kk < NT / 2; ++kk) {
    int k0 = 2 * kk;
    GROUP(k0, 0)
    GROUP(k0 + 1, 1)
  }
#undef GROUP
#undef STAGE_A
#undef STAGE_B
#undef RD_A
#undef RD_B

  // epilogue: acc -> LDS (bias+relu+bf16), then coalesced global stores
  #pragma unroll
  for (int n = 0; n < 4; ++n) {
    int gcl = wn * 64 + n * 16 + lr;
    float bv = bias[e * ND + n0 + gcl];
    #pragma unroll
    for (int m = 0; m < 8; ++m) {
      int trow = wm * 128 + m * 16 + lk8 * 4;
      #pragma unroll
      for (int j = 0; j < 4; ++j) {
        float v = acc[m][n][j] + bv;
        if (RELU) v = fmaxf(v, 0.f);
        sm.C[(trow + j) * 258 + gcl] = f2bf(v);
      }
    }
  }
  __syncthreads();
  #pragma unroll
  for (int i = 0; i < 16; ++i) {
    int chunk = i * 512 + tid;
    int row = chunk >> 5;
    int c8 = chunk & 31;
    short8 v = *reinterpret_cast<const short8*>(&sm.C[row * 258 + c8 * 8]);
    *reinterpret_cast<short8*>(
        &out[((size_t)(e * CAP + r0 + row)) * ND + n0 + c8 * 8]) = v;
  }
}

// ---------------- decode (+ loss in trailing block) ----------------
__global__ __launch_bounds__(256) void decode_kernel(
    const unsigned short* __restrict__ Y, const int* __restrict__ dest,
    const float* __restrict__ gn, float* __restrict__ y,
    const float* __restrict__ me_part, const int* __restrict__ ce_part,
    float* __restrict__ loss_out) {
  int tid = threadIdx.x;
  if (blockIdx.x == gridDim.x - 1) {
    int e = tid & 63, ch = tid >> 6;  // 4 chunks of GATE_BLKS/4 gating blocks
    float sme = 0.f, sce = 0.f;
    for (int j = 0; j < GATE_BLKS / 4; ++j) {
      int idx = (ch * (GATE_BLKS / 4) + j) * 64 + e;
      sme += me_part[idx];
      sce += (float)ce_part[idx];
    }
    __shared__ float redm[4][64];
    __shared__ float redc[4][64];
    redm[ch][e] = sme;
    redc[ch][e] = sce;
    __syncthreads();
    if (tid < 64) {
      float m = redm[0][tid] + redm[1][tid] + redm[2][tid] + redm[3][tid];
      float c = redc[0][tid] + redc[1][tid] + redc[2][tid] + redc[3][tid];
      float p = m * c;
      #pragma unroll
      for (int off = 32; off; off >>= 1) p += __shfl_xor(p, off);
      if (tid == 0) loss_out[0] = p * ((float)E_NUM / ((float)S_TOK * (float)S_TOK));
    }
    return;
  }
  int t = blockIdx.x * 4 + (tid >> 6);
  int m0 = (tid & 63) * 8;
  int d0 = dest[t * 2 + 0], d1 = dest[t * 2 + 1];
  float g0 = gn[t * 2 + 0], g1 = gn[t * 2 + 1];
  float o[8];
  #pragma unroll
  for (int j = 0; j < 8; ++j) o[j] = 0.f;
  if (d0 >= 0) {
    short8 v = *reinterpret_cast<const short8*>(&Y[(size_t)d0 * M_DIM + m0]);
    #pragma unroll
    for (int j = 0; j < 8; ++j) o[j] += g0 * bf2f((unsigned short)v[j]);
  }
  if (d1 >= 0) {
    short8 v = *reinterpret_cast<const short8*>(&Y[(size_t)d1 * M_DIM + m0]);
    #pragma unroll
    for (int j = 0; j < 8; ++j) o[j] += g1 * bf2f((unsigned short)v[j]);
  }
  float4 o0 = {o[0], o[1], o[2], o[3]};
  float4 o1 = {o[4], o[5], o[6], o[7]};
  *reinterpret_cast<float4*>(&y[(size_t)t * M_DIM + m0]) = o0;
  *reinterpret_cast<float4*>(&y[(size_t)t * M_DIM + m0 + 4]) = o1;
}

extern "C" void kernel_launch(void* const* d_in, const int* in_sizes, int n_in,
                              void* d_out, int out_size, void* d_ws, size_t ws_size,
                              hipStream_t stream) {
  const float* x     = (const float*)d_in[0];
  const float* wg    = (const float*)d_in[1];
  const float* fc1_w = (const float*)d_in[2];
  const float* fc1_b = (const float*)d_in[3];
  const float* fc2_w = (const float*)d_in[4];
  const float* fc2_b = (const float*)d_in[5];
  float* y = (float*)d_out;
  float* loss_out = y + (size_t)S_TOK * M_DIM;

  char* ws = (char*)d_ws;
  size_t off = 0;
  auto alloc = [&](size_t bytes) {
    char* p = ws + off;
    off += (bytes + 255) & ~(size_t)255;
    return p;
  };
  unsigned short* wT1 = (unsigned short*)alloc((size_t)E_NUM * V_DIM * M_DIM * 2);  // 128 MB
  unsigned short* wT2 = (unsigned short*)alloc((size_t)E_NUM * M_DIM * V_DIM * 2);  // 128 MB
  unsigned short* H   = (unsigned short*)alloc((size_t)E_NUM * CAP * V_DIM * 2);    // 256 MB
  unsigned short* xbf = (unsigned short*)alloc((size_t)S_TOK * M_DIM * 2);          // 32 MB
  float* wgT      = (float*)alloc((size_t)M_DIM * E_NUM * 4);                       // 128 KB
  int*   topk     = (int*)alloc((size_t)S_TOK * 2 * 4);
  float* gatesn   = (float*)alloc((size_t)S_TOK * 2 * 4);
  int*   dest     = (int*)alloc((size_t)S_TOK * 2 * 4);
  int*   slot_map = (int*)alloc((size_t)E_NUM * CAP * 4);
  float* me_part  = (float*)alloc((size_t)GATE_BLKS * 64 * 4);
  int*   ce_part  = (int*)alloc((size_t)GATE_BLKS * 64 * 4);
  // Y aliases wT1 (wT1 dead after gemm1; gemm2 writes Y, reads wT2+H)
  unsigned short* Y = wT1;

  // wg -> wgT (tiny, enables coalesced gating reads)
  wgt_kernel<<<(M_DIM * E_NUM) / 256, 256, 0, stream>>>(wg, wgT);

  // gating + both weight transposes, one launch (independent work overlapped)
  prep_kernel<<<GATE_BLKS + TR_BLKS, 256, 0, stream>>>(
      x, wgT, topk, gatesn, me_part, ce_part, xbf, fc1_w, wT1, fc2_w, wT2);

  rank_kernel<<<E_NUM, 256, 0, stream>>>(topk, dest, slot_map);

  // H = relu(gather(x) @ fc1 + b1): grid 2048, one expert per XCD at a time (L2-fit)
  gemm8_kernel<512, 2048, 8, 4, true, true>
      <<<E_NUM * 8 * 4, 512, 0, stream>>>(xbf, wT1, fc1_b, slot_map, H);
  // Y = H @ fc2 + b2 (NT=32; grid 512)
  gemm8_kernel<2048, 512, 2, 4, false, false>
      <<<E_NUM * 2 * 4, 512, 0, stream>>>(H, wT2, fc2_b, slot_map, Y);

  decode_kernel<<<S_TOK / 4 + 1, 256, 0, stream>>>(Y, dest, gatesn, y,
                                                   me_part, ce_part, loss_out);
}

// Round 17
// 728.332 us; speedup vs baseline: 1.0648x; 1.0648x over previous
//
#include <hip/hip_runtime.h>
#include <hip/hip_bf16.h>
#include <stdint.h>

#define S_TOK 32768
#define M_DIM 512
#define E_NUM 64
#define V_DIM 2048
#define CAP   1024

typedef __attribute__((ext_vector_type(8))) short short8;
typedef __attribute__((ext_vector_type(4))) float f32x4;

__device__ __forceinline__ unsigned short f2bf(float f) {
  unsigned int u = __float_as_uint(f);
  unsigned int r = (u + 0x7fffu + ((u >> 16) & 1u)) >> 16;
  return (unsigned short)r;
}
__device__ __forceinline__ float bf2f(unsigned short h) {
  return __uint_as_float(((unsigned int)h) << 16);
}

__device__ __forceinline__ void gload16(const void* g, void* lds) {
  __builtin_amdgcn_global_load_lds(
      (const __attribute__((address_space(1))) void*)g,
      (__attribute__((address_space(3))) void*)lds, 16, 0, 0);
}

// ---------------- wg [64][512] -> wgT [512][64] (one-time, 128 KB) ----------------
__global__ __launch_bounds__(256) void wgt_kernel(const float* __restrict__ wg,
                                                  float* __restrict__ wgT) {
  int idx = blockIdx.x * 256 + threadIdx.x;   // 0..32767
  int m = idx >> 6, e = idx & 63;
  wgT[idx] = wg[e * M_DIM + m];               // writes coalesced; reads once
}

// =========== prep: gating (blocks 0..2047) + both weight transposes ===========
#define GATE_BLKS (S_TOK / 16)           // 2048
#define TR_BLKS   16384                  // 8192 tiles per matrix (128x64 each)

struct PrepSmem {
  union {
    float ts[128][65];                   // transpose tile: 33.28 KB
    struct {
      float4 xs4[16 * 128];              // 16 tokens x 512 f32: 32 KB
      float mered[4][64];
      int cered[4][64];
    } g;
  };
};

__global__ __launch_bounds__(256) void prep_kernel(
    const float* __restrict__ x, const float* __restrict__ wgT,
    int* __restrict__ topk, float* __restrict__ gates_n,
    float* __restrict__ me_part, int* __restrict__ ce_part,
    unsigned short* __restrict__ xbf,
    const float* __restrict__ w1, unsigned short* __restrict__ o1,
    const float* __restrict__ w2, unsigned short* __restrict__ o2) {
  __shared__ PrepSmem sm;
  int tid = threadIdx.x;

  if (blockIdx.x >= GATE_BLKS) {
    // ---------------- transpose tile: 128 input-rows x 64 input-cols ----------------
    int t = blockIdx.x - GATE_BLKS;          // 0..16383
    int which = t >> 13;                     // 8192 tiles per matrix
    t &= 8191;
    int R = which ? V_DIM : M_DIM;           // input rows
    int Cc = which ? M_DIM : V_DIM;          // input cols
    int nbx = Cc / 64;
    int b = t >> 7;                          // 128 tiles per expert
    int tt = t & 127;
    const float* ip = (which ? w2 : w1) + (size_t)b * R * Cc;
    unsigned short* op = (which ? o2 : o1) + (size_t)b * R * Cc;
    int c0 = (tt % nbx) * 64, r0 = (tt / nbx) * 128;
    #pragma unroll
    for (int i = 0; i < 8; ++i) {
      int chunk = i * 256 + tid;
      int row = chunk >> 4;                  // 0..127
      int c4 = (chunk & 15) * 4;
      float4 v = *reinterpret_cast<const float4*>(&ip[(size_t)(r0 + row) * Cc + c0 + c4]);
      sm.ts[row][c4 + 0] = v.x; sm.ts[row][c4 + 1] = v.y;
      sm.ts[row][c4 + 2] = v.z; sm.ts[row][c4 + 3] = v.w;
    }
    __syncthreads();
    #pragma unroll
    for (int i = 0; i < 4; ++i) {
      int chunk = i * 256 + tid;
      int c = chunk >> 4;                    // 0..63 (output row)
      int m8 = (chunk & 15) * 8;             // 0..120 (output col group)
      short8 o;
      #pragma unroll
      for (int j = 0; j < 8; ++j) o[j] = (short)f2bf(sm.ts[m8 + j][c]);
      *reinterpret_cast<short8*>(&op[(size_t)(c0 + c) * R + r0 + m8]) = o;
    }
    return;
  }

  // ---------------- gating: 16 tokens/block, x in LDS, wgT coalesced ----------------
  int l = tid & 63, w = tid >> 6;
  int tb = blockIdx.x * 16;
  const float4* xg4 = reinterpret_cast<const float4*>(x) + (size_t)tb * 128;
  ushort4* xb4 = reinterpret_cast<ushort4*>(xbf) + (size_t)tb * 128;
  #pragma unroll
  for (int i = 0; i < 8; ++i) {
    float4 v = xg4[i * 256 + tid];
    sm.g.xs4[i * 256 + tid] = v;
    ushort4 o;
    o.x = f2bf(v.x); o.y = f2bf(v.y); o.z = f2bf(v.z); o.w = f2bf(v.w);
    xb4[i * 256 + tid] = o;   // fused x -> bf16
  }
  __syncthreads();

  // lane l = expert l; wgT[m][e] -> lanes read consecutive floats (coalesced),
  // 8-deep prefetch; x values broadcast from LDS.
  const float* wgtp = wgT + l;
  const float* xsf = reinterpret_cast<const float*>(sm.g.xs4);
  float acc[4] = {0.f, 0.f, 0.f, 0.f};
  for (int i0 = 0; i0 < 512; i0 += 8) {
    float wv[8];
    #pragma unroll
    for (int u = 0; u < 8; ++u) wv[u] = wgtp[(i0 + u) * 64];
    #pragma unroll
    for (int u = 0; u < 8; ++u) {
      #pragma unroll
      for (int t = 0; t < 4; ++t)
        acc[t] += xsf[(w * 4 + t) * 512 + i0 + u] * wv[u];
    }
  }

  float melocal = 0.f;
  int celocal = 0;
  for (int t = 0; t < 4; ++t) {
    float v = acc[t];
    float bv = v; int bi = l;
    #pragma unroll
    for (int off = 32; off; off >>= 1) {
      float ov = __shfl_xor(bv, off);
      int oi = __shfl_xor(bi, off);
      if (ov > bv || (ov == bv && oi < bi)) { bv = ov; bi = oi; }
    }
    float v2 = (l == bi) ? -INFINITY : v;
    float bv2 = v2; int bi2 = l;
    #pragma unroll
    for (int off = 32; off; off >>= 1) {
      float ov = __shfl_xor(bv2, off);
      int oi = __shfl_xor(bi2, off);
      if (ov > bv2 || (ov == bv2 && oi < bi2)) { bv2 = ov; bi2 = oi; }
    }
    float ex = expf(v - bv);
    float s = ex;
    #pragma unroll
    for (int off = 32; off; off >>= 1) s += __shfl_xor(s, off);
    melocal += ex / s;
    if (l == bi) celocal += 1;
    if (l == 0) {
      int sidx = tb + w * 4 + t;
      topk[sidx * 2 + 0] = bi;
      topk[sidx * 2 + 1] = bi2;
      float g1 = 1.0f / s;
      float g2 = expf(bv2 - bv) / s;
      float denom = fmaxf(g1 + g2, 1.1920929e-07f);
      gates_n[sidx * 2 + 0] = g1 / denom;
      gates_n[sidx * 2 + 1] = g2 / denom;
    }
  }
  sm.g.mered[w][l] = melocal;
  sm.g.cered[w][l] = celocal;
  __syncthreads();
  if (tid < 64) {
    me_part[blockIdx.x * 64 + tid] =
        sm.g.mered[0][tid] + sm.g.mered[1][tid] + sm.g.mered[2][tid] + sm.g.mered[3][tid];
    ce_part[blockIdx.x * 64 + tid] =
        sm.g.cered[0][tid] + sm.g.cered[1][tid] + sm.g.cered[2][tid] + sm.g.cered[3][tid];
  }
}

// ---------------- capacity ranking (self-initializing slot_map) ----------------
__global__ __launch_bounds__(256) void rank_kernel(const int* __restrict__ topk,
                                                   int* __restrict__ dest,
                                                   int* __restrict__ slot_map) {
  int e = blockIdx.x;
  int tid = threadIdx.x;
  int l = tid & 63, w = tid >> 6;
  int4 minus1 = {-1, -1, -1, -1};
  reinterpret_cast<int4*>(slot_map + e * CAP)[tid] = minus1;

  const int2* tk = reinterpret_cast<const int2*>(topk);
  int base = tid * 128;
  int c0 = 0, c1 = 0;
  for (int j = 0; j < 128; ++j) {
    int2 p = tk[base + j];
    c0 += (p.x == e); c1 += (p.y == e);
  }
  int i0 = c0, i1 = c1;
  #pragma unroll
  for (int off = 1; off < 64; off <<= 1) {
    int t0 = __shfl_up(i0, off);
    int t1 = __shfl_up(i1, off);
    if (l >= off) { i0 += t0; i1 += t1; }
  }
  __shared__ int ws0[4], ws1[4], wo0[4], wo1[4], tot0s;
  if (l == 63) { ws0[w] = i0; ws1[w] = i1; }
  __syncthreads();
  if (tid == 0) {
    int a = 0, b = 0;
    #pragma unroll
    for (int j = 0; j < 4; ++j) { wo0[j] = a; a += ws0[j]; wo1[j] = b; b += ws1[j]; }
    tot0s = a;
  }
  __syncthreads();
  int loc0 = wo0[w] + i0 - c0;
  int loc1 = tot0s + wo1[w] + i1 - c1;
  for (int j = 0; j < 128; ++j) {
    int s = base + j;
    int2 p = tk[s];
    if (p.x == e) {
      int d = (loc0 < CAP) ? e * CAP + loc0 : -1;
      dest[s * 2] = d;
      if (d >= 0) slot_map[d] = s;
      loc0++;
    }
    if (p.y == e) {
      int d = (loc1 < CAP) ? e * CAP + loc1 : -1;
      dest[s * 2 + 1] = d;
      if (d >= 0) slot_map[d] = s;
      loc1++;
    }
  }
}

// =================== 256x256 8-phase MFMA GEMM (T2+T3+T4+T5) — round-6 proven ===================
#define PH_TOP                                                                 \
  __builtin_amdgcn_sched_barrier(0);                                           \
  __builtin_amdgcn_s_barrier();                                                \
  asm volatile("s_waitcnt lgkmcnt(0)" ::: "memory");                           \
  __builtin_amdgcn_sched_barrier(0);                                           \
  __builtin_amdgcn_s_setprio(1);
#define PH_BOT                                                                 \
  __builtin_amdgcn_s_setprio(0);                                               \
  __builtin_amdgcn_sched_barrier(0);                                           \
  __builtin_amdgcn_s_barrier();

struct SmemGemm {
  union {
    struct {
      unsigned short A[2][256 * 64];
      unsigned short B[2][256 * 64];
    } st;
    unsigned short C[256 * 258];  // epilogue staging
  };
};

template <int KD, int ND, int NBX, int NBY, bool GATHER, bool RELU>
__global__ __launch_bounds__(512, 2) void gemm8_kernel(
    const unsigned short* __restrict__ A,
    const unsigned short* __restrict__ BT,
    const float* __restrict__ bias,
    const int* __restrict__ slot_map,
    unsigned short* __restrict__ out) {
  constexpr int NT = KD / 64;  // K-tiles
  __shared__ SmemGemm sm;

  const int tid = threadIdx.x;
  const int l = tid & 63;
  const int w = tid >> 6;
  const int wm = w >> 2;
  const int wn = w & 3;
  const int lr = l & 15;
  const int lk8 = l >> 4;

  // XCD-chunked bijective block swizzle: concurrent lids on one XCD = one expert (L2-fit)
  const int nwg = E_NUM * NBX * NBY;
  const int cpx = nwg >> 3;
  int lid = ((int)blockIdx.x % 8) * cpx + (int)blockIdx.x / 8;
  const int e = lid / (NBX * NBY);
  int rem = lid % (NBX * NBY);
  const int n0 = (rem / NBY) * 256;
  const int r0 = (rem % NBY) * 256;

  // stage swizzle: LDS group (l&7) at row r holds global colgroup (l&7)^(r&7)
  const int cg8 = (((l & 7) ^ (l >> 3)) * 8);

  uint32_t offA[2][2], offB[2][2], ldsA[2][2], ldsB[2][2];
  #pragma unroll
  for (int sel = 0; sel < 2; ++sel) {
    #pragma unroll
    for (int i = 0; i < 2; ++i) {
      int lr128 = i * 64 + w * 8 + (l >> 3);
      int ar = ((lr128 >> 6) * 128) + sel * 64 + (lr128 & 63);
      int br = ((lr128 >> 5) * 64) + sel * 32 + (lr128 & 31);
      ldsA[sel][i] = ar * 64 + (l & 7) * 8;
      ldsB[sel][i] = br * 64 + (l & 7) * 8;
      int arow;
      if (GATHER) {
        int s = slot_map[e * CAP + r0 + ar];
        if (s < 0) s = 0;  // unfilled slot: any valid row; output never read
        arow = s;
      } else {
        arow = e * CAP + r0 + ar;
      }
      offA[sel][i] = (uint32_t)arow * KD + cg8;
      offB[sel][i] = (uint32_t)(n0 + br) * KD + cg8;
    }
  }
  const unsigned short* Bexp = BT + (size_t)e * ND * KD;

  const int sg0 = ((0 + lk8) ^ (lr & 7)) * 8;
  const int sg1 = ((4 + lk8) ^ (lr & 7)) * 8;

#define STAGE_A(sel, p, kt)                                                    \
  do {                                                                         \
    gload16(A + offA[sel][0] + (kt) * 64, &sm.st.A[p][ldsA[sel][0]]);          \
    gload16(A + offA[sel][1] + (kt) * 64, &sm.st.A[p][ldsA[sel][1]]);          \
  } while (0)
#define STAGE_B(sel, p, kt)                                                    \
  do {                                                                         \
    gload16(Bexp + offB[sel][0] + (kt) * 64, &sm.st.B[p][ldsB[sel][0]]);       \
    gload16(Bexp + offB[sel][1] + (kt) * 64, &sm.st.B[p][ldsB[sel][1]]);       \
  } while (0)
#define RD_A(p, mh, mi, ks)                                                    \
  (*reinterpret_cast<const short8*>(                                           \
      &sm.st.A[p][(wm * 128 + (mh) * 64 + (mi) * 16 + lr) * 64 + ((ks) ? sg1 : sg0)]))
#define RD_B(p, nh, ni, ks)                                                    \
  (*reinterpret_cast<const short8*>(                                           \
      &sm.st.B[p][(wn * 64 + (nh) * 32 + (ni) * 16 + lr) * 64 + ((ks) ? sg1 : sg0)]))

  short8 afr[2][4][2];
  short8 bfr[2][2];
  f32x4 acc[8][4];
  f32x4 zero = {0.f, 0.f, 0.f, 0.f};
  #pragma unroll
  for (int m = 0; m < 8; ++m)
    #pragma unroll
    for (int n = 0; n < 4; ++n) acc[m][n] = zero;

  // prologue: tile0 complete + tile1 {Amh0, Amh1, Bnh0}  (14 vmem ops)
  STAGE_A(0, 0, 0); STAGE_A(1, 0, 0); STAGE_B(0, 0, 0); STAGE_B(1, 0, 0);
  STAGE_A(0, 1, 1); STAGE_A(1, 1, 1); STAGE_B(0, 1, 1);
  asm volatile("s_waitcnt vmcnt(6)" ::: "memory");
  __builtin_amdgcn_sched_barrier(0);
  __builtin_amdgcn_s_barrier();

#define GROUP(k, p)                                                            \
  {                                                                            \
    /* phase 1: quadrant (mh0, nh0); stage Bnh1(k+1) -> dbuf[p^1] */           \
    _Pragma("unroll") for (int mi = 0; mi < 4; ++mi) {                         \
      afr[0][mi][0] = RD_A(p, 0, mi, 0);                                       \
      afr[0][mi][1] = RD_A(p, 0, mi, 1);                                       \
    }                                                                          \
    _Pragma("unroll") for (int ni = 0; ni < 2; ++ni) {                         \
      bfr[ni][0] = RD_B(p, 0, ni, 0);                                          \
      bfr[ni][1] = RD_B(p, 0, ni, 1);                                          \
    }                                                                          \
    if ((k) + 1 < NT) { STAGE_B(1, (p) ^ 1, (k) + 1); }                        \
    PH_TOP                                                                     \
    _Pragma("unroll") for (int mi = 0; mi < 4; ++mi)                           \
      _Pragma("unroll") for (int ni = 0; ni < 2; ++ni) {                       \
        acc[mi][ni] = __builtin_amdgcn_mfma_f32_16x16x32_bf16(                 \
            afr[0][mi][0], bfr[ni][0], acc[mi][ni], 0, 0, 0);                  \
        acc[mi][ni] = __builtin_amdgcn_mfma_f32_16x16x32_bf16(                 \
            afr[0][mi][1], bfr[ni][1], acc[mi][ni], 0, 0, 0);                  \
      }                                                                        \
    PH_BOT                                                                     \
    /* phase 2: quadrant (mh1, nh0); stage Amh0(k+2) -> dbuf[p] */             \
    _Pragma("unroll") for (int mi = 0; mi < 4; ++mi) {                         \
      afr[1][mi][0] = RD_A(p, 1, mi, 0);                                       \
      afr[1][mi][1] = RD_A(p, 1, mi, 1);                                       \
    }                                                                          \
    if ((k) + 2 < NT) { STAGE_A(0, p, (k) + 2); }                              \
    PH_TOP                                                                     \
    _Pragma("unroll") for (int mi = 0; mi < 4; ++mi)                           \
      _Pragma("unroll") for (int ni = 0; ni < 2; ++ni) {                       \
        acc[4 + mi][ni] = __builtin_amdgcn_mfma_f32_16x16x32_bf16(             \
            afr[1][mi][0], bfr[ni][0], acc[4 + mi][ni], 0, 0, 0);              \
        acc[4 + mi][ni] = __builtin_amdgcn_mfma_f32_16x16x32_bf16(             \
            afr[1][mi][1], bfr[ni][1], acc[4 + mi][ni], 0, 0, 0);              \
      }                                                                        \
    PH_BOT                                                                     \
    /* phase 3: quadrant (mh0, nh1); stage Amh1(k+2) -> dbuf[p] */             \
    _Pragma("unroll") for (int ni = 0; ni < 2; ++ni) {                         \
      bfr[ni][0] = RD_B(p, 1, ni, 0);                                          \
      bfr[ni][1] = RD_B(p, 1, ni, 1);                                          \
    }                                                                          \
    if ((k) + 2 < NT) { STAGE_A(1, p, (k) + 2); }                              \
    PH_TOP                                                                     \
    _Pragma("unroll") for (int mi = 0; mi < 4; ++mi)                           \
      _Pragma("unroll") for (int ni = 0; ni < 2; ++ni) {                       \
        acc[mi][2 + ni] = __builtin_amdgcn_mfma_f32_16x16x32_bf16(             \
            afr[0][mi][0], bfr[ni][0], acc[mi][2 + ni], 0, 0, 0);              \
        acc[mi][2 + ni] = __builtin_amdgcn_mfma_f32_16x16x32_bf16(             \
            afr[0][mi][1], bfr[ni][1], acc[mi][2 + ni], 0, 0, 0);              \
      }                                                                        \
    PH_BOT                                                                     \
    /* phase 4: quadrant (mh1, nh1); stage Bnh0(k+2); counted vmcnt */         \
    if ((k) + 2 < NT) { STAGE_B(0, p, (k) + 2); }                              \
    __builtin_amdgcn_sched_barrier(0);                                         \
    __builtin_amdgcn_s_barrier();                                              \
    __builtin_amdgcn_s_setprio(1);                                             \
    _Pragma("unroll") for (int mi = 0; mi < 4; ++mi)                           \
      _Pragma("unroll") for (int ni = 0; ni < 2; ++ni) {                       \
        acc[4 + mi][2 + ni] = __builtin_amdgcn_mfma_f32_16x16x32_bf16(         \
            afr[1][mi][0], bfr[ni][0], acc[4 + mi][2 + ni], 0, 0, 0);          \
        acc[4 + mi][2 + ni] = __builtin_amdgcn_mfma_f32_16x16x32_bf16(         \
            afr[1][mi][1], bfr[ni][1], acc[4 + mi][2 + ni], 0, 0, 0);          \
      }                                                                        \
    __builtin_amdgcn_s_setprio(0);                                             \
    __builtin_amdgcn_sched_barrier(0);                                         \
    if ((k) + 2 < NT) {                                                        \
      asm volatile("s_waitcnt vmcnt(6)" ::: "memory");                         \
    } else {                                                                   \
      asm volatile("s_waitcnt vmcnt(0)" ::: "memory");                         \
    }                                                                          \
    __builtin_amdgcn_sched_barrier(0);                                         \
    __builtin_amdgcn_s_barrier();                                              \
  }

  for (int kk = 0; kk < NT / 2; ++kk) {
    int k0 = 2 * kk;
    GROUP(k0, 0)
    GROUP(k0 + 1, 1)
  }
#undef GROUP
#undef STAGE_A
#undef STAGE_B
#undef RD_A
#undef RD_B

  // epilogue: acc -> LDS (bias+relu+bf16), then coalesced global stores
  #pragma unroll
  for (int n = 0; n < 4; ++n) {
    int gcl = wn * 64 + n * 16 + lr;
    float bv = bias[e * ND + n0 + gcl];
    #pragma unroll
    for (int m = 0; m < 8; ++m) {
      int trow = wm * 128 + m * 16 + lk8 * 4;
      #pragma unroll
      for (int j = 0; j < 4; ++j) {
        float v = acc[m][n][j] + bv;
        if (RELU) v = fmaxf(v, 0.f);
        sm.C[(trow + j) * 258 + gcl] = f2bf(v);
      }
    }
  }
  __syncthreads();
  #pragma unroll
  for (int i = 0; i < 16; ++i) {
    int chunk = i * 512 + tid;
    int row = chunk >> 5;
    int c8 = chunk & 31;
    short8 v = *reinterpret_cast<const short8*>(&sm.C[row * 258 + c8 * 8]);
    *reinterpret_cast<short8*>(
        &out[((size_t)(e * CAP + r0 + row)) * ND + n0 + c8 * 8]) = v;
  }
}

// ---------------- decode (+ loss in trailing block) ----------------
__global__ __launch_bounds__(256) void decode_kernel(
    const unsigned short* __restrict__ Y, const int* __restrict__ dest,
    const float* __restrict__ gn, float* __restrict__ y,
    const float* __restrict__ me_part, const int* __restrict__ ce_part,
    float* __restrict__ loss_out) {
  int tid = threadIdx.x;
  if (blockIdx.x == gridDim.x - 1) {
    int e = tid & 63, ch = tid >> 6;  // 4 chunks of 512
    float sme = 0.f, sce = 0.f;
    for (int j = 0; j < 512; ++j) {
      int idx = (ch * 512 + j) * 64 + e;
      sme += me_part[idx];
      sce += (float)ce_part[idx];
    }
    __shared__ float redm[4][64];
    __shared__ float redc[4][64];
    redm[ch][e] = sme;
    redc[ch][e] = sce;
    __syncthreads();
    if (tid < 64) {
      float m = redm[0][tid] + redm[1][tid] + redm[2][tid] + redm[3][tid];
      float c = redc[0][tid] + redc[1][tid] + redc[2][tid] + redc[3][tid];
      float p = m * c;
      #pragma unroll
      for (int off = 32; off; off >>= 1) p += __shfl_xor(p, off);
      if (tid == 0) loss_out[0] = p * ((float)E_NUM / ((float)S_TOK * (float)S_TOK));
    }
    return;
  }
  int t = blockIdx.x * 4 + (tid >> 6);
  int m0 = (tid & 63) * 8;
  int d0 = dest[t * 2 + 0], d1 = dest[t * 2 + 1];
  float g0 = gn[t * 2 + 0], g1 = gn[t * 2 + 1];
  float o[8];
  #pragma unroll
  for (int j = 0; j < 8; ++j) o[j] = 0.f;
  if (d0 >= 0) {
    short8 v = *reinterpret_cast<const short8*>(&Y[(size_t)d0 * M_DIM + m0]);
    #pragma unroll
    for (int j = 0; j < 8; ++j) o[j] += g0 * bf2f((unsigned short)v[j]);
  }
  if (d1 >= 0) {
    short8 v = *reinterpret_cast<const short8*>(&Y[(size_t)d1 * M_DIM + m0]);
    #pragma unroll
    for (int j = 0; j < 8; ++j) o[j] += g1 * bf2f((unsigned short)v[j]);
  }
  float4 o0 = {o[0], o[1], o[2], o[3]};
  float4 o1 = {o[4], o[5], o[6], o[7]};
  *reinterpret_cast<float4*>(&y[(size_t)t * M_DIM + m0]) = o0;
  *reinterpret_cast<float4*>(&y[(size_t)t * M_DIM + m0 + 4]) = o1;
}

extern "C" void kernel_launch(void* const* d_in, const int* in_sizes, int n_in,
                              void* d_out, int out_size, void* d_ws, size_t ws_size,
                              hipStream_t stream) {
  const float* x     = (const float*)d_in[0];
  const float* wg    = (const float*)d_in[1];
  const float* fc1_w = (const float*)d_in[2];
  const float* fc1_b = (const float*)d_in[3];
  const float* fc2_w = (const float*)d_in[4];
  const float* fc2_b = (const float*)d_in[5];
  float* y = (float*)d_out;
  float* loss_out = y + (size_t)S_TOK * M_DIM;

  char* ws = (char*)d_ws;
  size_t off = 0;
  auto alloc = [&](size_t bytes) {
    char* p = ws + off;
    off += (bytes + 255) & ~(size_t)255;
    return p;
  };
  unsigned short* wT1 = (unsigned short*)alloc((size_t)E_NUM * V_DIM * M_DIM * 2);  // 128 MB
  unsigned short* wT2 = (unsigned short*)alloc((size_t)E_NUM * M_DIM * V_DIM * 2);  // 128 MB
  unsigned short* H   = (unsigned short*)alloc((size_t)E_NUM * CAP * V_DIM * 2);    // 256 MB
  unsigned short* xbf = (unsigned short*)alloc((size_t)S_TOK * M_DIM * 2);          // 32 MB
  float* wgT      = (float*)alloc((size_t)M_DIM * E_NUM * 4);                       // 128 KB
  int*   topk     = (int*)alloc((size_t)S_TOK * 2 * 4);
  float* gatesn   = (float*)alloc((size_t)S_TOK * 2 * 4);
  int*   dest     = (int*)alloc((size_t)S_TOK * 2 * 4);
  int*   slot_map = (int*)alloc((size_t)E_NUM * CAP * 4);
  float* me_part  = (float*)alloc((size_t)GATE_BLKS * 64 * 4);
  int*   ce_part  = (int*)alloc((size_t)GATE_BLKS * 64 * 4);
  // Y aliases wT1 (wT1 dead after gemm1; gemm2 writes Y, reads wT2+H)
  unsigned short* Y = wT1;

  // wg -> wgT (tiny, enables coalesced gating reads)
  wgt_kernel<<<(M_DIM * E_NUM) / 256, 256, 0, stream>>>(wg, wgT);

  // gating + both weight transposes, one launch (independent work overlapped)
  prep_kernel<<<GATE_BLKS + TR_BLKS, 256, 0, stream>>>(
      x, wgT, topk, gatesn, me_part, ce_part, xbf, fc1_w, wT1, fc2_w, wT2);

  rank_kernel<<<E_NUM, 256, 0, stream>>>(topk, dest, slot_map);

  // H = relu(gather(x) @ fc1 + b1): grid 2048, one expert per XCD at a time (L2-fit)
  gemm8_kernel<512, 2048, 8, 4, true, true>
      <<<E_NUM * 8 * 4, 512, 0, stream>>>(xbf, wT1, fc1_b, slot_map, H);
  // Y = H @ fc2 + b2 (NT=32; grid 512)
  gemm8_kernel<2048, 512, 2, 4, false, false>
      <<<E_NUM * 2 * 4, 512, 0, stream>>>(H, wT2, fc2_b, slot_map, Y);

  decode_kernel<<<S_TOK / 4 + 1, 256, 0, stream>>>(Y, dest, gatesn, y,
                                                   me_part, ce_part, loss_out);
}